// Round 6
// baseline (435.321 us; speedup 1.0000x reference)
//
#include <hip/hip_runtime.h>

#define N_USERS 400000
#define N_ITEMS 200000
#define NNODES  600000   // N_USERS + N_ITEMS
#define D 64
#define B 8192
#define NBKT 8

// ---------------------------------------------------------------------------
// bf16 helpers
// ---------------------------------------------------------------------------
__device__ __forceinline__ float bflo(unsigned u) { return __uint_as_float(u << 16); }
__device__ __forceinline__ float bfhi(unsigned u) { return __uint_as_float(u & 0xffff0000u); }
__device__ __forceinline__ unsigned f2bf(float f) {   // round-to-nearest-even
    unsigned u = __float_as_uint(f);
    unsigned r = u + 0x7fffu + ((u >> 16) & 1u);
    return r >> 16;
}

// acc[0..7] += v * bf16x8(word4)
__device__ __forceinline__ void unpack_fma(float* acc, uint4 wv, float v) {
    acc[0] += v * bflo(wv.x); acc[1] += v * bfhi(wv.x);
    acc[2] += v * bflo(wv.y); acc[3] += v * bfhi(wv.y);
    acc[4] += v * bflo(wv.z); acc[5] += v * bfhi(wv.z);
    acc[6] += v * bflo(wv.w); acc[7] += v * bfhi(wv.w);
}

// Bucket map balanced by expected edge count:
// users (avg deg 1.5): 4 buckets x 100K rows; items (avg deg 3): 4 x 50K rows.
__device__ __forceinline__ int bucket_of(int r) {
    return (r < N_USERS) ? (r / 100000) : (4 + (r - N_USERS) / 50000);
}

// ---------------------------------------------------------------------------
// scans
// ---------------------------------------------------------------------------
__global__ void k_scan1(int* __restrict__ deg, int* __restrict__ sums,
                        float* __restrict__ dinv, int n) {
    __shared__ int lds[256];
    int i = blockIdx.x * 256 + threadIdx.x;
    int v = (i < n) ? deg[i] : 0;
    if (i < n) dinv[i] = (v > 0) ? (float)(1.0 / sqrt((double)v)) : 0.0f;
    lds[threadIdx.x] = v;
    __syncthreads();
    for (int off = 1; off < 256; off <<= 1) {
        int t = (threadIdx.x >= off) ? lds[threadIdx.x - off] : 0;
        __syncthreads();
        lds[threadIdx.x] += t;
        __syncthreads();
    }
    int inc = lds[threadIdx.x];
    if (i < n) deg[i] = inc - v;
    if (threadIdx.x == 255) sums[blockIdx.x] = inc;
}

__global__ void k_scan2(int* __restrict__ sums, int n) {
    __shared__ int lds[1024];
    __shared__ int carry;
    if (threadIdx.x == 0) carry = 0;
    __syncthreads();
    for (int base = 0; base < n; base += 1024) {
        int i = base + threadIdx.x;
        int v = (i < n) ? sums[i] : 0;
        lds[threadIdx.x] = v;
        __syncthreads();
        for (int off = 1; off < 1024; off <<= 1) {
            int t = (threadIdx.x >= off) ? lds[threadIdx.x - off] : 0;
            __syncthreads();
            lds[threadIdx.x] += t;
            __syncthreads();
        }
        int inc = lds[threadIdx.x];
        if (i < n) sums[i] = (inc - v) + carry;
        __syncthreads();
        if (threadIdx.x == 1023) carry += lds[1023];
        __syncthreads();
    }
}

__global__ void k_scan3(const int* __restrict__ deg, const int* __restrict__ sums,
                        int* __restrict__ row_ptr, int* __restrict__ nextp, int nnz) {
    int i = blockIdx.x * blockDim.x + threadIdx.x;
    if (i >= NNODES) return;
    int rp = deg[i] + sums[i >> 8];
    row_ptr[i] = rp;
    nextp[i] = rp;
    if (i == 0) row_ptr[NNODES] = nnz;
}

// ---------------------------------------------------------------------------
// FAT1: XCD-filtered deg histogram || mask-popcount streaming || sample seed.
// (R5 structure - validated: light blocks, no LDS, XCD-local atomics.)
// ---------------------------------------------------------------------------
__global__ void k_fat1(const int* __restrict__ rows,
                       const int* __restrict__ um, const int* __restrict__ im,
                       int* __restrict__ sizes, int* __restrict__ deg,
                       const int* __restrict__ users, const int* __restrict__ pos,
                       const int* __restrict__ neg,
                       char* __restrict__ flag1, char* __restrict__ flag2, int nnz) {
    int bid = blockIdx.x;
    int x = bid & 7;
    int g = bid >> 3;
    int st = g / 17;
    int slot = g - st * 17;
    int t = threadIdx.x;
    if (slot < 8) {
        int e = (st * 8 + slot) * 256 + t;
        if (e >= nnz) return;
        int r = rows[e];
        if (bucket_of(r) == x) atomicAdd(&deg[r], 1);
    } else if (slot < 16) {
        int sb = (st * 8 + (slot - 8)) * 8 + x;
        int gtid = sb * 256 + t;
        int r = gtid >> 4;
        int q = gtid & 15;
        if (r >= NNODES) return;
        const int4* p = (const int4*)((r < N_USERS) ? um + (size_t)r * D
                                                    : im + (size_t)(r - N_USERS) * D);
        int4 v = p[q];
        int s = v.x + v.y + v.z + v.w;
        s += __shfl_xor(s, 1);
        s += __shfl_xor(s, 2);
        s += __shfl_xor(s, 4);
        s += __shfl_xor(s, 8);
        if (q == 0) sizes[r] = s;
    } else {
        int slot2 = (st * 8 + x) * 256 + t;
        if (slot2 >= 3 * B) return;
        int set = slot2 / B;
        int b = slot2 - set * B;
        int r;
        if (set == 0)      r = users[b];
        else if (set == 1) r = N_USERS + pos[b];
        else               r = N_USERS + neg[b];
        flag2[r] = 1;
        flag1[r] = 1;
    }
}

// ---------------------------------------------------------------------------
// FAT2: XCD-filtered scatter || COO mark-pass1. (R5 structure - validated.)
// pass1 race: monotone 0->1 flags, benign superset (R2 note).
// ---------------------------------------------------------------------------
__global__ void k_fat2(const int* __restrict__ rows, const int* __restrict__ cols,
                       int* __restrict__ nextp, int* __restrict__ pcol,
                       char* __restrict__ flag2, int nnz) {
    int bid = blockIdx.x;
    int x = bid & 7;
    int g = bid >> 3;
    int st = g / 9;
    int slot = g - st * 9;
    int t = threadIdx.x;
    if (slot < 8) {
        int e = (st * 8 + slot) * 256 + t;
        if (e >= nnz) return;
        int r = rows[e];
        if (bucket_of(r) != x) return;
        int p = atomicAdd(&nextp[r], 1);
        pcol[p] = cols[e];
    } else {
        int e = (st * 8 + x) * 256 + t;
        if (e >= nnz) return;
        if (flag2[rows[e]]) flag2[cols[e]] = 1;
    }
}

// ---------------------------------------------------------------------------
// COO mark pass2 + wl2 build: flag1[col]=1 for edges with flag2[row];
// tail: flag1 |= flag2 AND append flag2 rows to wl2 (flag2 stable here;
// per-lane atomicAdd(cnt,1) is wave-coalesced by the compiler).
// ---------------------------------------------------------------------------
__global__ void k_pass2(const int* __restrict__ rows, const int* __restrict__ cols,
                        const char* __restrict__ flag2, char* __restrict__ flag1,
                        int* __restrict__ wl2, int* __restrict__ wl2_cnt, int nnz) {
    int t = blockIdx.x * blockDim.x + threadIdx.x;
    if (t < nnz) {
        if (flag2[rows[t]]) flag1[cols[t]] = 1;
    } else {
        int r = t - nnz;
        if (r < NNODES) {
            if (flag2[r]) {
                flag1[r] = 1;
                int p = atomicAdd(wl2_cnt, 1);
                wl2[p] = r;
            }
        }
    }
}

// ---------------------------------------------------------------------------
// wl1 build: compact flag1 rows into a dense worklist (latency-hiding lever:
// spmm waves become 100% working rows -> ~3x outstanding misses).
// ---------------------------------------------------------------------------
__global__ void k_wl1(const char* __restrict__ flag1, int* __restrict__ wl1,
                      int* __restrict__ wl1_cnt) {
    int r = blockIdx.x * blockDim.x + threadIdx.x;
    if (r >= NNODES) return;
    if (!flag1[r]) return;
    int p = atomicAdd(wl1_cnt, 1);
    wl1[p] = r;
}

// ---------------------------------------------------------------------------
// Layer-1 SPMM over the wl1 worklist (dense waves). 8 threads/row, unroll x2.
// ---------------------------------------------------------------------------
__global__ void k_spmm1(const int* __restrict__ row_ptr, const int* __restrict__ pcol,
                        const float* __restrict__ dinv, const int* __restrict__ sizes,
                        const int* __restrict__ wl1, const int* __restrict__ wl1_cnt,
                        const float* __restrict__ ue, const float* __restrict__ ie,
                        unsigned* __restrict__ y1) {
    int tid = blockIdx.x * blockDim.x + threadIdx.x;
    int w = tid >> 3;
    if (w >= *wl1_cnt) return;
    int r = wl1[w];
    int c8 = (tid & 7) << 3;          // f32 col base
    int s = row_ptr[r];
    int e = row_ptr[r + 1];
    float dr = dinv[r];
    float acc[8] = {0.f, 0.f, 0.f, 0.f, 0.f, 0.f, 0.f, 0.f};
    int i = s;
    for (; i + 1 < e; i += 2) {
        int c0 = pcol[i], c1 = pcol[i + 1];
        float v0 = dr * dinv[c0], v1 = dr * dinv[c1];
        int sz0 = sizes[c0], sz1 = sizes[c1];
        const float* p0 = ((c0 < N_USERS) ? ue + (size_t)c0 * D
                                          : ie + (size_t)(c0 - N_USERS) * D) + c8;
        const float* p1 = ((c1 < N_USERS) ? ue + (size_t)c1 * D
                                          : ie + (size_t)(c1 - N_USERS) * D) + c8;
        float4 a0 = *(const float4*)p0;
        float4 a1 = *(const float4*)(p0 + 4);
        float4 b0 = *(const float4*)p1;
        float4 b1 = *(const float4*)(p1 + 4);
        acc[0] += v0 * ((c8 + 0 < sz0) ? a0.x : 0.f) + v1 * ((c8 + 0 < sz1) ? b0.x : 0.f);
        acc[1] += v0 * ((c8 + 1 < sz0) ? a0.y : 0.f) + v1 * ((c8 + 1 < sz1) ? b0.y : 0.f);
        acc[2] += v0 * ((c8 + 2 < sz0) ? a0.z : 0.f) + v1 * ((c8 + 2 < sz1) ? b0.z : 0.f);
        acc[3] += v0 * ((c8 + 3 < sz0) ? a0.w : 0.f) + v1 * ((c8 + 3 < sz1) ? b0.w : 0.f);
        acc[4] += v0 * ((c8 + 4 < sz0) ? a1.x : 0.f) + v1 * ((c8 + 4 < sz1) ? b1.x : 0.f);
        acc[5] += v0 * ((c8 + 5 < sz0) ? a1.y : 0.f) + v1 * ((c8 + 5 < sz1) ? b1.y : 0.f);
        acc[6] += v0 * ((c8 + 6 < sz0) ? a1.z : 0.f) + v1 * ((c8 + 6 < sz1) ? b1.z : 0.f);
        acc[7] += v0 * ((c8 + 7 < sz0) ? a1.w : 0.f) + v1 * ((c8 + 7 < sz1) ? b1.w : 0.f);
    }
    if (i < e) {
        int c = pcol[i];
        float v = dr * dinv[c];
        int sz = sizes[c];
        const float* p = ((c < N_USERS) ? ue + (size_t)c * D
                                        : ie + (size_t)(c - N_USERS) * D) + c8;
        float4 e0 = *(const float4*)p;
        float4 e1 = *(const float4*)(p + 4);
        acc[0] += v * ((c8 + 0 < sz) ? e0.x : 0.f);
        acc[1] += v * ((c8 + 1 < sz) ? e0.y : 0.f);
        acc[2] += v * ((c8 + 2 < sz) ? e0.z : 0.f);
        acc[3] += v * ((c8 + 3 < sz) ? e0.w : 0.f);
        acc[4] += v * ((c8 + 4 < sz) ? e1.x : 0.f);
        acc[5] += v * ((c8 + 5 < sz) ? e1.y : 0.f);
        acc[6] += v * ((c8 + 6 < sz) ? e1.z : 0.f);
        acc[7] += v * ((c8 + 7 < sz) ? e1.w : 0.f);
    }
    uint4 o;
    o.x = f2bf(acc[0]) | (f2bf(acc[1]) << 16);
    o.y = f2bf(acc[2]) | (f2bf(acc[3]) << 16);
    o.z = f2bf(acc[4]) | (f2bf(acc[5]) << 16);
    o.w = f2bf(acc[6]) | (f2bf(acc[7]) << 16);
    *(uint4*)(y1 + (size_t)r * 32 + (tid & 7) * 4) = o;
}

// ---------------------------------------------------------------------------
// Layer-2 bf16 SPMM over the wl2 worklist: x2[r] = sum val * y1[col].
// ---------------------------------------------------------------------------
__global__ void k_spmm2(const int* __restrict__ row_ptr, const int* __restrict__ pcol,
                        const float* __restrict__ dinv,
                        const int* __restrict__ wl2, const int* __restrict__ wl2_cnt,
                        const unsigned* __restrict__ y1, unsigned* __restrict__ x2) {
    int tid = blockIdx.x * blockDim.x + threadIdx.x;
    int w = tid >> 3;
    if (w >= *wl2_cnt) return;
    int r = wl2[w];
    int cp = (tid & 7) << 2;
    int s = row_ptr[r];
    int e = row_ptr[r + 1];
    float dr = dinv[r];
    float acc[8] = {0.f, 0.f, 0.f, 0.f, 0.f, 0.f, 0.f, 0.f};
    int i = s;
    for (; i + 1 < e; i += 2) {
        int c0 = pcol[i], c1 = pcol[i + 1];
        float v0 = dr * dinv[c0], v1 = dr * dinv[c1];
        uint4 w0 = *(const uint4*)(y1 + (size_t)c0 * 32 + cp);
        uint4 w1 = *(const uint4*)(y1 + (size_t)c1 * 32 + cp);
        unpack_fma(acc, w0, v0);
        unpack_fma(acc, w1, v1);
    }
    if (i < e) {
        int c0 = pcol[i];
        float v0 = dr * dinv[c0];
        uint4 w0 = *(const uint4*)(y1 + (size_t)c0 * 32 + cp);
        unpack_fma(acc, w0, v0);
    }
    uint4 o;
    o.x = f2bf(acc[0]) | (f2bf(acc[1]) << 16);
    o.y = f2bf(acc[2]) | (f2bf(acc[3]) << 16);
    o.z = f2bf(acc[4]) | (f2bf(acc[5]) << 16);
    o.w = f2bf(acc[6]) | (f2bf(acc[7]) << 16);
    *(uint4*)(x2 + (size_t)r * 32 + cp) = o;
}

// ---------------------------------------------------------------------------
// Final sampled layer, fused epilogue + ego.
// ---------------------------------------------------------------------------
__global__ void k_spmm3(const int* __restrict__ row_ptr, const int* __restrict__ pcol,
                        const float* __restrict__ dinv, const int* __restrict__ sizes,
                        const float* __restrict__ ue, const float* __restrict__ ie,
                        const unsigned* __restrict__ y1, const unsigned* __restrict__ x2,
                        const int* __restrict__ users, const int* __restrict__ pos,
                        const int* __restrict__ neg, float* __restrict__ out) {
    int tid = blockIdx.x * blockDim.x + threadIdx.x;
    int slot = tid >> 3;
    if (slot >= 3 * B) return;
    int cp = (tid & 7) << 2;          // uint base
    int c8 = (tid & 7) << 3;          // f32 col base
    int set = slot / B;
    int b = slot - set * B;
    int r;
    if (set == 0)      r = users[b];
    else if (set == 1) r = N_USERS + pos[b];
    else               r = N_USERS + neg[b];
    int s = row_ptr[r];
    int e = row_ptr[r + 1];
    float dr = dinv[r];
    float acc[8] = {0.f, 0.f, 0.f, 0.f, 0.f, 0.f, 0.f, 0.f};
    uint4 g1 = *(const uint4*)(y1 + (size_t)r * 32 + cp);
    uint4 g2 = *(const uint4*)(x2 + (size_t)r * 32 + cp);
    unpack_fma(acc, g1, 1.0f);
    unpack_fma(acc, g2, 1.0f);
    int i = s;
    for (; i + 1 < e; i += 2) {
        int c0 = pcol[i], c1 = pcol[i + 1];
        float v0 = dr * dinv[c0], v1 = dr * dinv[c1];
        uint4 w0 = *(const uint4*)(x2 + (size_t)c0 * 32 + cp);
        uint4 w1 = *(const uint4*)(x2 + (size_t)c1 * 32 + cp);
        unpack_fma(acc, w0, v0);
        unpack_fma(acc, w1, v1);
    }
    if (i < e) {
        int c0 = pcol[i];
        float v0 = dr * dinv[c0];
        uint4 w0 = *(const uint4*)(x2 + (size_t)c0 * 32 + cp);
        unpack_fma(acc, w0, v0);
    }
    const float* p = ((r < N_USERS) ? ue + (size_t)r * D
                                    : ie + (size_t)(r - N_USERS) * D) + c8;
    float4 e0 = *(const float4*)p;
    float4 e1 = *(const float4*)(p + 4);
    int sz = sizes[r];
    e0.x = (c8 + 0 < sz) ? e0.x : 0.f; e0.y = (c8 + 1 < sz) ? e0.y : 0.f;
    e0.z = (c8 + 2 < sz) ? e0.z : 0.f; e0.w = (c8 + 3 < sz) ? e0.w : 0.f;
    e1.x = (c8 + 4 < sz) ? e1.x : 0.f; e1.y = (c8 + 5 < sz) ? e1.y : 0.f;
    e1.z = (c8 + 6 < sz) ? e1.z : 0.f; e1.w = (c8 + 7 < sz) ? e1.w : 0.f;
    float4 oa, ob;
    oa.x = (e0.x + acc[0]) * 0.25f; oa.y = (e0.y + acc[1]) * 0.25f;
    oa.z = (e0.z + acc[2]) * 0.25f; oa.w = (e0.w + acc[3]) * 0.25f;
    ob.x = (e1.x + acc[4]) * 0.25f; ob.y = (e1.y + acc[5]) * 0.25f;
    ob.z = (e1.z + acc[6]) * 0.25f; ob.w = (e1.w + acc[7]) * 0.25f;
    float* o0 = out + (size_t)slot * D + c8;
    float* o1 = out + (size_t)(3 * B + slot) * D + c8;
    *(float4*)o0 = oa; *(float4*)(o0 + 4) = ob;
    *(float4*)o1 = e0; *(float4*)(o1 + 4) = e1;
}

extern "C" void kernel_launch(void* const* d_in, const int* in_sizes, int n_in,
                              void* d_out, int out_size, void* d_ws, size_t ws_size,
                              hipStream_t stream) {
    const float* ue   = (const float*)d_in[0];
    const float* ie   = (const float*)d_in[1];
    const int*   um   = (const int*)d_in[2];
    const int*   im   = (const int*)d_in[3];
    const int*   rows = (const int*)d_in[4];
    const int*   cols = (const int*)d_in[5];
    const int*   users = (const int*)d_in[7];
    const int*   pos   = (const int*)d_in[8];
    const int*   neg   = (const int*)d_in[9];
    int nnz = in_sizes[4];

    float* out = (float*)d_out;

    // workspace layout (16B-aligned bf16 node buffers first)
    unsigned short* Y1 = (unsigned short*)d_ws;         // NNODES*D bf16
    unsigned short* X2 = Y1 + (size_t)NNODES * D;       // NNODES*D bf16
    int*   deg     = (int*)(X2 + (size_t)NNODES * D);   // NNODES
    int*   row_ptr = deg + NNODES;                      // NNODES+1
    int*   nextp   = row_ptr + NNODES + 1;              // NNODES
    int*   sizes   = nextp + NNODES;                    // NNODES
    int*   sums    = sizes + NNODES;                    // up to 4096
    int*   wcnt    = sums + 4096;                       // [0]=wl1_cnt [1]=wl2_cnt
    float* dinv    = (float*)(wcnt + 16);               // NNODES
    int*   pcol    = (int*)(dinv + NNODES);             // nnz
    char*  flag1   = (char*)(pcol + nnz);               // NNODES
    char*  flag2   = flag1 + NNODES;                    // NNODES
    int*   wl1     = (int*)(((uintptr_t)(flag2 + NNODES) + 15) & ~(uintptr_t)15);
    int*   wl2     = wl1 + NNODES;

    const int blk = 256;
    const int scan_blocks = (NNODES + 255) / 256;       // 2344
    int chunks = (nnz + 255) / 256;                     // 4688
    int nst = (chunks + 7) / 8;                         // 586 supertiles

    hipMemsetAsync(deg, 0, (size_t)NNODES * sizeof(int), stream);
    hipMemsetAsync(wcnt, 0, 16 * sizeof(int), stream);
    hipMemsetAsync(flag1, 0, (size_t)2 * NNODES, stream);

    // --- FAT1: histX || sizes || seed ---
    k_fat1<<<nst * 17 * 8, blk, 0, stream>>>(rows, um, im, sizes, deg,
                                             users, pos, neg, flag1, flag2, nnz);

    // --- scans ---
    k_scan1<<<scan_blocks, 256, 0, stream>>>(deg, sums, dinv, NNODES);
    k_scan2<<<1, 1024, 0, stream>>>(sums, scan_blocks);
    k_scan3<<<(NNODES + blk - 1) / blk, blk, 0, stream>>>(deg, sums, row_ptr, nextp, nnz);

    // --- FAT2: scatterX || mark-pass1 ---
    k_fat2<<<nst * 9 * 8, blk, 0, stream>>>(rows, cols, nextp, pcol, flag2, nnz);

    // --- mark pass2 (+ wl2 build) ---
    k_pass2<<<(nnz + NNODES + blk - 1) / blk, blk, 0, stream>>>(rows, cols, flag2, flag1,
                                                                wl2, wcnt + 1, nnz);

    // --- wl1 build ---
    k_wl1<<<(NNODES + blk - 1) / blk, blk, 0, stream>>>(flag1, wl1, wcnt);

    int n_full = NNODES * 8;
    int n_samp = 3 * B * 8;

    // layer 1 over wl1 (dense waves)
    k_spmm1<<<(n_full + blk - 1) / blk, blk, 0, stream>>>(row_ptr, pcol, dinv, sizes,
                                                          wl1, wcnt,
                                                          ue, ie, (unsigned*)Y1);
    // layer 2 over wl2 (dense waves)
    k_spmm2<<<(n_full + blk - 1) / blk, blk, 0, stream>>>(row_ptr, pcol, dinv,
                                                          wl2, wcnt + 1,
                                                          (const unsigned*)Y1, (unsigned*)X2);
    // layer 3: sampled rows, fused epilogue + ego
    k_spmm3<<<(n_samp + blk - 1) / blk, blk, 0, stream>>>(row_ptr, pcol, dinv, sizes,
                                                          ue, ie,
                                                          (const unsigned*)Y1,
                                                          (const unsigned*)X2,
                                                          users, pos, neg, out);
}

// Round 7
// 234.023 us; speedup vs baseline: 1.8602x; 1.8602x over previous
//
#include <hip/hip_runtime.h>

#define N_USERS 400000
#define N_ITEMS 200000
#define NNODES  600000   // N_USERS + N_ITEMS
#define D 64
#define B 8192
#define NBKT 8

// ---------------------------------------------------------------------------
// bf16 helpers
// ---------------------------------------------------------------------------
__device__ __forceinline__ float bflo(unsigned u) { return __uint_as_float(u << 16); }
__device__ __forceinline__ float bfhi(unsigned u) { return __uint_as_float(u & 0xffff0000u); }
__device__ __forceinline__ unsigned f2bf(float f) {   // round-to-nearest-even
    unsigned u = __float_as_uint(f);
    unsigned r = u + 0x7fffu + ((u >> 16) & 1u);
    return r >> 16;
}

// acc[0..7] += v * bf16x8(word4)
__device__ __forceinline__ void unpack_fma(float* acc, uint4 wv, float v) {
    acc[0] += v * bflo(wv.x); acc[1] += v * bfhi(wv.x);
    acc[2] += v * bflo(wv.y); acc[3] += v * bfhi(wv.y);
    acc[4] += v * bflo(wv.z); acc[5] += v * bfhi(wv.z);
    acc[6] += v * bflo(wv.w); acc[7] += v * bfhi(wv.w);
}

// Bucket map balanced by expected edge count:
// users (avg deg 1.5): 4 buckets x 100K rows; items (avg deg 3): 4 x 50K rows.
__device__ __forceinline__ int bucket_of(int r) {
    return (r < N_USERS) ? (r / 100000) : (4 + (r - N_USERS) / 50000);
}

// ---------------------------------------------------------------------------
// scans
// ---------------------------------------------------------------------------
__global__ void k_scan1(int* __restrict__ deg, int* __restrict__ sums,
                        float* __restrict__ dinv, int n) {
    __shared__ int lds[256];
    int i = blockIdx.x * 256 + threadIdx.x;
    int v = (i < n) ? deg[i] : 0;
    if (i < n) dinv[i] = (v > 0) ? (float)(1.0 / sqrt((double)v)) : 0.0f;
    lds[threadIdx.x] = v;
    __syncthreads();
    for (int off = 1; off < 256; off <<= 1) {
        int t = (threadIdx.x >= off) ? lds[threadIdx.x - off] : 0;
        __syncthreads();
        lds[threadIdx.x] += t;
        __syncthreads();
    }
    int inc = lds[threadIdx.x];
    if (i < n) deg[i] = inc - v;
    if (threadIdx.x == 255) sums[blockIdx.x] = inc;
}

__global__ void k_scan2(int* __restrict__ sums, int n) {
    __shared__ int lds[1024];
    __shared__ int carry;
    if (threadIdx.x == 0) carry = 0;
    __syncthreads();
    for (int base = 0; base < n; base += 1024) {
        int i = base + threadIdx.x;
        int v = (i < n) ? sums[i] : 0;
        lds[threadIdx.x] = v;
        __syncthreads();
        for (int off = 1; off < 1024; off <<= 1) {
            int t = (threadIdx.x >= off) ? lds[threadIdx.x - off] : 0;
            __syncthreads();
            lds[threadIdx.x] += t;
            __syncthreads();
        }
        int inc = lds[threadIdx.x];
        if (i < n) sums[i] = (inc - v) + carry;
        __syncthreads();
        if (threadIdx.x == 1023) carry += lds[1023];
        __syncthreads();
    }
}

__global__ void k_scan3(const int* __restrict__ deg, const int* __restrict__ sums,
                        int* __restrict__ row_ptr, int* __restrict__ nextp, int nnz) {
    int i = blockIdx.x * blockDim.x + threadIdx.x;
    if (i >= NNODES) return;
    int rp = deg[i] + sums[i >> 8];
    row_ptr[i] = rp;
    nextp[i] = rp;
    if (i == 0) row_ptr[NNODES] = nnz;
}

// ---------------------------------------------------------------------------
// FAT1: XCD-filtered deg histogram || mask-popcount streaming || sample seed.
// (R5 structure - validated: light blocks, no LDS, XCD-local atomics.)
// ---------------------------------------------------------------------------
__global__ void k_fat1(const int* __restrict__ rows,
                       const int* __restrict__ um, const int* __restrict__ im,
                       int* __restrict__ sizes, int* __restrict__ deg,
                       const int* __restrict__ users, const int* __restrict__ pos,
                       const int* __restrict__ neg,
                       char* __restrict__ flag1, char* __restrict__ flag2, int nnz) {
    int bid = blockIdx.x;
    int x = bid & 7;
    int g = bid >> 3;
    int st = g / 17;
    int slot = g - st * 17;
    int t = threadIdx.x;
    if (slot < 8) {
        int e = (st * 8 + slot) * 256 + t;
        if (e >= nnz) return;
        int r = rows[e];
        if (bucket_of(r) == x) atomicAdd(&deg[r], 1);
    } else if (slot < 16) {
        int sb = (st * 8 + (slot - 8)) * 8 + x;
        int gtid = sb * 256 + t;
        int r = gtid >> 4;
        int q = gtid & 15;
        if (r >= NNODES) return;
        const int4* p = (const int4*)((r < N_USERS) ? um + (size_t)r * D
                                                    : im + (size_t)(r - N_USERS) * D);
        int4 v = p[q];
        int s = v.x + v.y + v.z + v.w;
        s += __shfl_xor(s, 1);
        s += __shfl_xor(s, 2);
        s += __shfl_xor(s, 4);
        s += __shfl_xor(s, 8);
        if (q == 0) sizes[r] = s;
    } else {
        int slot2 = (st * 8 + x) * 256 + t;
        if (slot2 >= 3 * B) return;
        int set = slot2 / B;
        int b = slot2 - set * B;
        int r;
        if (set == 0)      r = users[b];
        else if (set == 1) r = N_USERS + pos[b];
        else               r = N_USERS + neg[b];
        flag2[r] = 1;
        flag1[r] = 1;
    }
}

// ---------------------------------------------------------------------------
// FAT2: XCD-filtered scatter || COO mark-pass1. (R5 structure - validated.)
// pass1 race: monotone 0->1 flags, benign superset (R2 note).
// ---------------------------------------------------------------------------
__global__ void k_fat2(const int* __restrict__ rows, const int* __restrict__ cols,
                       int* __restrict__ nextp, int* __restrict__ pcol,
                       char* __restrict__ flag2, int nnz) {
    int bid = blockIdx.x;
    int x = bid & 7;
    int g = bid >> 3;
    int st = g / 9;
    int slot = g - st * 9;
    int t = threadIdx.x;
    if (slot < 8) {
        int e = (st * 8 + slot) * 256 + t;
        if (e >= nnz) return;
        int r = rows[e];
        if (bucket_of(r) != x) return;
        int p = atomicAdd(&nextp[r], 1);
        pcol[p] = cols[e];
    } else {
        int e = (st * 8 + x) * 256 + t;
        if (e >= nnz) return;
        if (flag2[rows[e]]) flag2[cols[e]] = 1;
    }
}

// ---------------------------------------------------------------------------
// COO mark pass2 + per-block flag2 counts.
// Edge blocks: flag1[col]=1 for edges with flag2[row].
// Tail blocks (aligned 256-row tiles): flag1 |= flag2, cnt2[tb] = ballot-count.
// NO global atomic counter (R6's 115us single-counter serialization lesson).
// ---------------------------------------------------------------------------
__global__ void k_pass2(const int* __restrict__ rows, const int* __restrict__ cols,
                        const char* __restrict__ flag2, char* __restrict__ flag1,
                        int* __restrict__ cnt2, int nnz, int eb) {
    int bid = blockIdx.x;
    int t = threadIdx.x;
    if (bid < eb) {
        int e = bid * 256 + t;
        if (e < nnz && flag2[rows[e]]) flag1[cols[e]] = 1;
        return;
    }
    int tb = bid - eb;
    int r = tb * 256 + t;
    char f = (r < NNODES) ? flag2[r] : 0;
    if (f) flag1[r] = 1;
    unsigned long long bal = __ballot(f != 0);
    __shared__ int ws[4];
    int lane = t & 63, wv = t >> 6;
    if (lane == 0) ws[wv] = (int)__popcll(bal);
    __syncthreads();
    if (t == 0) cnt2[tb] = ws[0] + ws[1] + ws[2] + ws[3];
}

// per-block flag1 counts (flag1 stable after pass2)
__global__ void k_cnt1(const char* __restrict__ flag1, int* __restrict__ cnt1) {
    int tb = blockIdx.x;
    int t = threadIdx.x;
    int r = tb * 256 + t;
    char f = (r < NNODES) ? flag1[r] : 0;
    unsigned long long bal = __ballot(f != 0);
    __shared__ int ws[4];
    int lane = t & 63, wv = t >> 6;
    if (lane == 0) ws[wv] = (int)__popcll(bal);
    __syncthreads();
    if (t == 0) cnt1[tb] = ws[0] + ws[1] + ws[2] + ws[3];
}

// single-block exclusive scan of TWO count arrays (in place) + totals
__global__ void k_scan_dual(int* __restrict__ a, int* __restrict__ b, int n,
                            int* __restrict__ totA, int* __restrict__ totB) {
    __shared__ int lds[1024];
    __shared__ int carry;
    for (int pass = 0; pass < 2; ++pass) {
        int* arr = pass ? b : a;
        if (threadIdx.x == 0) carry = 0;
        __syncthreads();
        for (int base = 0; base < n; base += 1024) {
            int i = base + threadIdx.x;
            int v = (i < n) ? arr[i] : 0;
            lds[threadIdx.x] = v;
            __syncthreads();
            for (int off = 1; off < 1024; off <<= 1) {
                int t = (threadIdx.x >= off) ? lds[threadIdx.x - off] : 0;
                __syncthreads();
                lds[threadIdx.x] += t;
                __syncthreads();
            }
            int inc = lds[threadIdx.x];
            if (i < n) arr[i] = (inc - v) + carry;
            __syncthreads();
            if (threadIdx.x == 1023) carry += lds[1023];
            __syncthreads();
        }
        if (threadIdx.x == 0) { if (pass) *totB = carry; else *totA = carry; }
        __syncthreads();
    }
}

// ballot-rank fill of both worklists (sorted order -> pcol/y1 locality)
__global__ void k_fill(const char* __restrict__ flag1, const char* __restrict__ flag2,
                       const int* __restrict__ cnt1, const int* __restrict__ cnt2,
                       int* __restrict__ wl1, int* __restrict__ wl2) {
    int tb = blockIdx.x;
    int t = threadIdx.x;
    int r = tb * 256 + t;
    bool a = (r < NNODES) && flag1[r];
    bool b = (r < NNODES) && flag2[r];
    int lane = t & 63, wv = t >> 6;
    unsigned long long lt = (1ull << lane) - 1ull;
    unsigned long long ba = __ballot(a);
    unsigned long long bb = __ballot(b);
    __shared__ int wa[4], wb[4];
    if (lane == 0) { wa[wv] = (int)__popcll(ba); wb[wv] = (int)__popcll(bb); }
    __syncthreads();
    int offA = 0, offB = 0;
    for (int i = 0; i < wv; ++i) { offA += wa[i]; offB += wb[i]; }
    if (a) wl1[cnt1[tb] + offA + (int)__popcll(ba & lt)] = r;
    if (b) wl2[cnt2[tb] + offB + (int)__popcll(bb & lt)] = r;
}

// ---------------------------------------------------------------------------
// Layer-1 SPMM over the wl1 worklist (dense waves). 8 threads/row, unroll x2.
// ---------------------------------------------------------------------------
__global__ void k_spmm1(const int* __restrict__ row_ptr, const int* __restrict__ pcol,
                        const float* __restrict__ dinv, const int* __restrict__ sizes,
                        const int* __restrict__ wl1, const int* __restrict__ wl1_cnt,
                        const float* __restrict__ ue, const float* __restrict__ ie,
                        unsigned* __restrict__ y1) {
    int tid = blockIdx.x * blockDim.x + threadIdx.x;
    int w = tid >> 3;
    if (w >= *wl1_cnt) return;
    int r = wl1[w];
    int c8 = (tid & 7) << 3;          // f32 col base
    int s = row_ptr[r];
    int e = row_ptr[r + 1];
    float dr = dinv[r];
    float acc[8] = {0.f, 0.f, 0.f, 0.f, 0.f, 0.f, 0.f, 0.f};
    int i = s;
    for (; i + 1 < e; i += 2) {
        int c0 = pcol[i], c1 = pcol[i + 1];
        float v0 = dr * dinv[c0], v1 = dr * dinv[c1];
        int sz0 = sizes[c0], sz1 = sizes[c1];
        const float* p0 = ((c0 < N_USERS) ? ue + (size_t)c0 * D
                                          : ie + (size_t)(c0 - N_USERS) * D) + c8;
        const float* p1 = ((c1 < N_USERS) ? ue + (size_t)c1 * D
                                          : ie + (size_t)(c1 - N_USERS) * D) + c8;
        float4 a0 = *(const float4*)p0;
        float4 a1 = *(const float4*)(p0 + 4);
        float4 b0 = *(const float4*)p1;
        float4 b1 = *(const float4*)(p1 + 4);
        acc[0] += v0 * ((c8 + 0 < sz0) ? a0.x : 0.f) + v1 * ((c8 + 0 < sz1) ? b0.x : 0.f);
        acc[1] += v0 * ((c8 + 1 < sz0) ? a0.y : 0.f) + v1 * ((c8 + 1 < sz1) ? b0.y : 0.f);
        acc[2] += v0 * ((c8 + 2 < sz0) ? a0.z : 0.f) + v1 * ((c8 + 2 < sz1) ? b0.z : 0.f);
        acc[3] += v0 * ((c8 + 3 < sz0) ? a0.w : 0.f) + v1 * ((c8 + 3 < sz1) ? b0.w : 0.f);
        acc[4] += v0 * ((c8 + 4 < sz0) ? a1.x : 0.f) + v1 * ((c8 + 4 < sz1) ? b1.x : 0.f);
        acc[5] += v0 * ((c8 + 5 < sz0) ? a1.y : 0.f) + v1 * ((c8 + 5 < sz1) ? b1.y : 0.f);
        acc[6] += v0 * ((c8 + 6 < sz0) ? a1.z : 0.f) + v1 * ((c8 + 6 < sz1) ? b1.z : 0.f);
        acc[7] += v0 * ((c8 + 7 < sz0) ? a1.w : 0.f) + v1 * ((c8 + 7 < sz1) ? b1.w : 0.f);
    }
    if (i < e) {
        int c = pcol[i];
        float v = dr * dinv[c];
        int sz = sizes[c];
        const float* p = ((c < N_USERS) ? ue + (size_t)c * D
                                        : ie + (size_t)(c - N_USERS) * D) + c8;
        float4 e0 = *(const float4*)p;
        float4 e1 = *(const float4*)(p + 4);
        acc[0] += v * ((c8 + 0 < sz) ? e0.x : 0.f);
        acc[1] += v * ((c8 + 1 < sz) ? e0.y : 0.f);
        acc[2] += v * ((c8 + 2 < sz) ? e0.z : 0.f);
        acc[3] += v * ((c8 + 3 < sz) ? e0.w : 0.f);
        acc[4] += v * ((c8 + 4 < sz) ? e1.x : 0.f);
        acc[5] += v * ((c8 + 5 < sz) ? e1.y : 0.f);
        acc[6] += v * ((c8 + 6 < sz) ? e1.z : 0.f);
        acc[7] += v * ((c8 + 7 < sz) ? e1.w : 0.f);
    }
    uint4 o;
    o.x = f2bf(acc[0]) | (f2bf(acc[1]) << 16);
    o.y = f2bf(acc[2]) | (f2bf(acc[3]) << 16);
    o.z = f2bf(acc[4]) | (f2bf(acc[5]) << 16);
    o.w = f2bf(acc[6]) | (f2bf(acc[7]) << 16);
    *(uint4*)(y1 + (size_t)r * 32 + (tid & 7) * 4) = o;
}

// ---------------------------------------------------------------------------
// Layer-2 bf16 SPMM over the wl2 worklist: x2[r] = sum val * y1[col].
// ---------------------------------------------------------------------------
__global__ void k_spmm2(const int* __restrict__ row_ptr, const int* __restrict__ pcol,
                        const float* __restrict__ dinv,
                        const int* __restrict__ wl2, const int* __restrict__ wl2_cnt,
                        const unsigned* __restrict__ y1, unsigned* __restrict__ x2) {
    int tid = blockIdx.x * blockDim.x + threadIdx.x;
    int w = tid >> 3;
    if (w >= *wl2_cnt) return;
    int r = wl2[w];
    int cp = (tid & 7) << 2;
    int s = row_ptr[r];
    int e = row_ptr[r + 1];
    float dr = dinv[r];
    float acc[8] = {0.f, 0.f, 0.f, 0.f, 0.f, 0.f, 0.f, 0.f};
    int i = s;
    for (; i + 1 < e; i += 2) {
        int c0 = pcol[i], c1 = pcol[i + 1];
        float v0 = dr * dinv[c0], v1 = dr * dinv[c1];
        uint4 w0 = *(const uint4*)(y1 + (size_t)c0 * 32 + cp);
        uint4 w1 = *(const uint4*)(y1 + (size_t)c1 * 32 + cp);
        unpack_fma(acc, w0, v0);
        unpack_fma(acc, w1, v1);
    }
    if (i < e) {
        int c0 = pcol[i];
        float v0 = dr * dinv[c0];
        uint4 w0 = *(const uint4*)(y1 + (size_t)c0 * 32 + cp);
        unpack_fma(acc, w0, v0);
    }
    uint4 o;
    o.x = f2bf(acc[0]) | (f2bf(acc[1]) << 16);
    o.y = f2bf(acc[2]) | (f2bf(acc[3]) << 16);
    o.z = f2bf(acc[4]) | (f2bf(acc[5]) << 16);
    o.w = f2bf(acc[6]) | (f2bf(acc[7]) << 16);
    *(uint4*)(x2 + (size_t)r * 32 + cp) = o;
}

// ---------------------------------------------------------------------------
// Final sampled layer, fused epilogue + ego.
// ---------------------------------------------------------------------------
__global__ void k_spmm3(const int* __restrict__ row_ptr, const int* __restrict__ pcol,
                        const float* __restrict__ dinv, const int* __restrict__ sizes,
                        const float* __restrict__ ue, const float* __restrict__ ie,
                        const unsigned* __restrict__ y1, const unsigned* __restrict__ x2,
                        const int* __restrict__ users, const int* __restrict__ pos,
                        const int* __restrict__ neg, float* __restrict__ out) {
    int tid = blockIdx.x * blockDim.x + threadIdx.x;
    int slot = tid >> 3;
    if (slot >= 3 * B) return;
    int cp = (tid & 7) << 2;          // uint base
    int c8 = (tid & 7) << 3;          // f32 col base
    int set = slot / B;
    int b = slot - set * B;
    int r;
    if (set == 0)      r = users[b];
    else if (set == 1) r = N_USERS + pos[b];
    else               r = N_USERS + neg[b];
    int s = row_ptr[r];
    int e = row_ptr[r + 1];
    float dr = dinv[r];
    float acc[8] = {0.f, 0.f, 0.f, 0.f, 0.f, 0.f, 0.f, 0.f};
    uint4 g1 = *(const uint4*)(y1 + (size_t)r * 32 + cp);
    uint4 g2 = *(const uint4*)(x2 + (size_t)r * 32 + cp);
    unpack_fma(acc, g1, 1.0f);
    unpack_fma(acc, g2, 1.0f);
    int i = s;
    for (; i + 1 < e; i += 2) {
        int c0 = pcol[i], c1 = pcol[i + 1];
        float v0 = dr * dinv[c0], v1 = dr * dinv[c1];
        uint4 w0 = *(const uint4*)(x2 + (size_t)c0 * 32 + cp);
        uint4 w1 = *(const uint4*)(x2 + (size_t)c1 * 32 + cp);
        unpack_fma(acc, w0, v0);
        unpack_fma(acc, w1, v1);
    }
    if (i < e) {
        int c0 = pcol[i];
        float v0 = dr * dinv[c0];
        uint4 w0 = *(const uint4*)(x2 + (size_t)c0 * 32 + cp);
        unpack_fma(acc, w0, v0);
    }
    const float* p = ((r < N_USERS) ? ue + (size_t)r * D
                                    : ie + (size_t)(r - N_USERS) * D) + c8;
    float4 e0 = *(const float4*)p;
    float4 e1 = *(const float4*)(p + 4);
    int sz = sizes[r];
    e0.x = (c8 + 0 < sz) ? e0.x : 0.f; e0.y = (c8 + 1 < sz) ? e0.y : 0.f;
    e0.z = (c8 + 2 < sz) ? e0.z : 0.f; e0.w = (c8 + 3 < sz) ? e0.w : 0.f;
    e1.x = (c8 + 4 < sz) ? e1.x : 0.f; e1.y = (c8 + 5 < sz) ? e1.y : 0.f;
    e1.z = (c8 + 6 < sz) ? e1.z : 0.f; e1.w = (c8 + 7 < sz) ? e1.w : 0.f;
    float4 oa, ob;
    oa.x = (e0.x + acc[0]) * 0.25f; oa.y = (e0.y + acc[1]) * 0.25f;
    oa.z = (e0.z + acc[2]) * 0.25f; oa.w = (e0.w + acc[3]) * 0.25f;
    ob.x = (e1.x + acc[4]) * 0.25f; ob.y = (e1.y + acc[5]) * 0.25f;
    ob.z = (e1.z + acc[6]) * 0.25f; ob.w = (e1.w + acc[7]) * 0.25f;
    float* o0 = out + (size_t)slot * D + c8;
    float* o1 = out + (size_t)(3 * B + slot) * D + c8;
    *(float4*)o0 = oa; *(float4*)(o0 + 4) = ob;
    *(float4*)o1 = e0; *(float4*)(o1 + 4) = e1;
}

extern "C" void kernel_launch(void* const* d_in, const int* in_sizes, int n_in,
                              void* d_out, int out_size, void* d_ws, size_t ws_size,
                              hipStream_t stream) {
    const float* ue   = (const float*)d_in[0];
    const float* ie   = (const float*)d_in[1];
    const int*   um   = (const int*)d_in[2];
    const int*   im   = (const int*)d_in[3];
    const int*   rows = (const int*)d_in[4];
    const int*   cols = (const int*)d_in[5];
    const int*   users = (const int*)d_in[7];
    const int*   pos   = (const int*)d_in[8];
    const int*   neg   = (const int*)d_in[9];
    int nnz = in_sizes[4];

    float* out = (float*)d_out;

    // workspace layout (16B-aligned bf16 node buffers first)
    unsigned short* Y1 = (unsigned short*)d_ws;         // NNODES*D bf16
    unsigned short* X2 = Y1 + (size_t)NNODES * D;       // NNODES*D bf16
    int*   deg     = (int*)(X2 + (size_t)NNODES * D);   // NNODES
    int*   row_ptr = deg + NNODES;                      // NNODES+1
    int*   nextp   = row_ptr + NNODES + 1;              // NNODES
    int*   sizes   = nextp + NNODES;                    // NNODES
    int*   sums    = sizes + NNODES;                    // up to 4096
    int*   wcnt    = sums + 4096;                       // [0]=wl1_cnt [1]=wl2_cnt
    int*   cnt1    = wcnt + 16;                         // 2344 (+pad)
    int*   cnt2    = cnt1 + 2360;                       // 2344 (+pad)
    float* dinv    = (float*)(cnt2 + 2360);             // NNODES
    int*   pcol    = (int*)(dinv + NNODES);             // nnz
    char*  flag1   = (char*)(pcol + nnz);               // NNODES
    char*  flag2   = flag1 + NNODES;                    // NNODES
    int*   wl1     = (int*)(((uintptr_t)(flag2 + NNODES) + 15) & ~(uintptr_t)15);
    int*   wl2     = wl1 + NNODES;

    const int blk = 256;
    const int scan_blocks = (NNODES + 255) / 256;       // 2344
    int chunks = (nnz + 255) / 256;                     // 4688
    int nst = (chunks + 7) / 8;                         // 586 supertiles

    hipMemsetAsync(deg, 0, (size_t)NNODES * sizeof(int), stream);
    hipMemsetAsync(flag1, 0, (size_t)2 * NNODES, stream);

    // --- FAT1: histX || sizes || seed ---
    k_fat1<<<nst * 17 * 8, blk, 0, stream>>>(rows, um, im, sizes, deg,
                                             users, pos, neg, flag1, flag2, nnz);

    // --- scans ---
    k_scan1<<<scan_blocks, 256, 0, stream>>>(deg, sums, dinv, NNODES);
    k_scan2<<<1, 1024, 0, stream>>>(sums, scan_blocks);
    k_scan3<<<(NNODES + blk - 1) / blk, blk, 0, stream>>>(deg, sums, row_ptr, nextp, nnz);

    // --- FAT2: scatterX || mark-pass1 ---
    k_fat2<<<nst * 9 * 8, blk, 0, stream>>>(rows, cols, nextp, pcol, flag2, nnz);

    // --- mark pass2 (+ per-block flag2 counts) ---
    k_pass2<<<chunks + scan_blocks, blk, 0, stream>>>(rows, cols, flag2, flag1,
                                                      cnt2, nnz, chunks);

    // --- worklist compaction: count flag1, dual scan, ballot-rank fill ---
    k_cnt1<<<scan_blocks, blk, 0, stream>>>(flag1, cnt1);
    k_scan_dual<<<1, 1024, 0, stream>>>(cnt1, cnt2, scan_blocks, wcnt, wcnt + 1);
    k_fill<<<scan_blocks, blk, 0, stream>>>(flag1, flag2, cnt1, cnt2, wl1, wl2);

    int n_full = NNODES * 8;
    int n_samp = 3 * B * 8;

    // layer 1 over wl1 (dense sorted waves)
    k_spmm1<<<(n_full + blk - 1) / blk, blk, 0, stream>>>(row_ptr, pcol, dinv, sizes,
                                                          wl1, wcnt,
                                                          ue, ie, (unsigned*)Y1);
    // layer 2 over wl2 (dense sorted waves)
    k_spmm2<<<(n_full + blk - 1) / blk, blk, 0, stream>>>(row_ptr, pcol, dinv,
                                                          wl2, wcnt + 1,
                                                          (const unsigned*)Y1, (unsigned*)X2);
    // layer 3: sampled rows, fused epilogue + ego
    k_spmm3<<<(n_samp + blk - 1) / blk, blk, 0, stream>>>(row_ptr, pcol, dinv, sizes,
                                                          ue, ie,
                                                          (const unsigned*)Y1,
                                                          (const unsigned*)X2,
                                                          users, pos, neg, out);
}